// Round 15
// baseline (504799.512 us; speedup 1.0000x reference)
//
#include <hip/hip_runtime.h>
#include <math.h>

// SNN language model forward — BITWISE fp32-numpy emulation.
// Decision-critical ops replicate numpy/BLAS fp32 arithmetic:
//   * matmuls: one fp32 accumulator per output element, serial ascending K, FMA
//     (= OpenBLAS/Eigen GEMM per-element order), each matmul rounded separately
//   * elementwise: every op individually rounded (no contraction)
//   * sigmoid = 1/(1+exp(-x)), softplus = max(x,0)+log1p(exp(-|x|)) with
//     correctly-rounded float transcendentals (glibc-style) via double emulation
// Smooth path (decoder/RMS/logits) plain fp32. Multi-kernel (guaranteed order).
// B=8, D=512, H=1024, L=4, K=8, S=64, VOCAB=6144.

#define BB  8
#define DD  512
#define HH  1024
#define LL  4
#define KK  8
#define SEQ 64
#define VV  6144

struct Prm {
  const int*   tok;
  const float *embed, *norm_w, *encW, *encb, *decW, *decb;
  const float *Win, *Wbx, *Wax, *Wtx, *WbV, *WaV, *WtV;
  const float *bb, *ba, *bt, *Wg, *Ws, *Wo, *wn;
  float* out;
  float* V;        // [2][L][B][H] double-buffered by bit parity
  float* vo;       // [L][B][D]
  float *sp, *sbuf, *bits, *dec, *hd, *y;
};

// correctly-rounded float transcendentals (glibc expf/log1pf behavior)
__device__ __forceinline__ float expf_cr(float x) {
  return (float)exp((double)x);
}
__device__ __forceinline__ float log1pf_cr(float x) {
  return (float)log1p((double)x);
}
__device__ __forceinline__ float sig_np(float x) {
  const float t = expf_cr(-x);              // rounded fp32
  const float u = __fadd_rn(1.f, t);        // rounded fp32
  return 1.f / u;                           // IEEE fp32 division
}
__device__ __forceinline__ float sp_np(float x) {
  const float ax = fabsf(x);
  const float t = expf_cr(-ax);
  const float u = log1pf_cr(t);
  return __fadd_rn(fmaxf(x, 0.f), u);
}

// ---- encoder: h0 = sigmoid(emb @ encW.T + encb); bit planes; dec = 0 ----
// grid: B x D
__global__ void k_enc(Prm p, int ti)
{
  const int b = blockIdx.x, d = threadIdx.x;
  const int tok = p.tok[b * SEQ + ti];
  const float* er = p.embed + (size_t)tok * DD;
  const float* wr = p.encW + (size_t)d * DD;
  float acc = 0.f;
  for (int j = 0; j < DD; ++j) acc = fmaf(er[j], wr[j], acc);   // serial-K FMA
  const float z = __fadd_rn(acc, p.encb[d]);
  float r = sig_np(z);
  for (int kk = 0; kk < KK; ++kk) {
    const float bit = (r >= 0.5f) ? 1.f : 0.f;
    p.bits[((size_t)kk * BB + b) * DD + d] = bit;
    r = __fmul_rn(__fsub_rn(r, __fmul_rn(0.5f, bit)), 2.f);     // exact anyway
  }
  p.dec[b * DD + d] = 0.f;
}

// ---- P1: per (b,i). Four s-dots + three V-dots, EACH its own accumulator ----
// grid: 32 x 256 = 8192
__global__ void k_p1(Prm p, int l, int rb, const float* __restrict__ s_in)
{
  const int id = blockIdx.x * 256 + threadIdx.x;
  const int b = id >> 10, i = id & 1023;
  const float* s  = s_in + b * DD;
  const float* Vr = p.V + (((size_t)rb * LL + l) * BB + b) * HH;
  const size_t rD = ((size_t)l * HH + i) * DD;
  const size_t rH = ((size_t)l * HH + i) * HH;

  float u = 0.f, zbs = 0.f, zas = 0.f, zts = 0.f;
  for (int j = 0; j < DD; ++j) {
    const float sv = s[j];
    u   = fmaf(sv, p.Win[rD + j], u);
    zbs = fmaf(sv, p.Wbx[rD + j], zbs);
    zas = fmaf(sv, p.Wax[rD + j], zas);
    zts = fmaf(sv, p.Wtx[rD + j], zts);
  }
  float zbv = 0.f, zav = 0.f, ztv = 0.f;
  for (int j = 0; j < HH; ++j) {
    const float vv = Vr[j];
    zbv = fmaf(vv, p.WbV[rH + j], zbv);
    zav = fmaf(vv, p.WaV[rH + j], zav);
    ztv = fmaf(vv, p.WtV[rH + j], ztv);
  }
  // (s@W.T + V@W.T) + bias, each matmul separately rounded already
  const float zb = __fadd_rn(__fadd_rn(zbs, zbv), p.bb[l * HH + i]);
  const float za = __fadd_rn(__fadd_rn(zas, zav), p.ba[l * HH + i]);
  const float zt = __fadd_rn(__fadd_rn(zts, ztv), p.bt[l * HH + i]);
  const float beta  = sig_np(zb);
  const float alpha = sig_np(za);
  const float vth   = __fadd_rn(0.1f, sp_np(zt));
  const float Vn0   = __fadd_rn(__fmul_rn(beta, Vr[i]), __fmul_rn(alpha, u));
  const float spv   = (Vn0 >= vth) ? 1.f : 0.f;
  const float Vn    = __fsub_rn(Vn0, __fmul_rn(spv, vth));
  p.V[(((size_t)(1 - rb) * LL + l) * BB + b) * HH + i] = Vn;
  p.sp[b * HH + i] = spv;
}

// ---- P2: per (b,d). gate/out/skip dots separate; output LIF ----
// grid: 16 x 256 = 4096
__global__ void k_p2(Prm p, int l, float wk, int lastL,
                     const float* __restrict__ s_in, float* __restrict__ s_out)
{
  const int id = blockIdx.x * 256 + threadIdx.x;
  const int b = id >> 9, d = id & 511;
  const float* s  = s_in + b * DD;
  const float* sp = p.sp + b * HH;
  const size_t rH = ((size_t)l * DD + d) * HH;
  const size_t rD = ((size_t)l * DD + d) * DD;

  float po = 0.f;
  for (int j = 0; j < HH; ++j) po = fmaf(sp[j], p.Wo[rH + j], po);
  float pg = 0.f, ps = 0.f;
  for (int j = 0; j < DD; ++j) {
    const float sv = s[j];
    pg = fmaf(sv, p.Wg[rD + j], pg);
    ps = fmaf(sv, p.Ws[rD + j], ps);
  }
  const float g  = sig_np(pg);
  const float h  = __fadd_rn(__fmul_rn(g, po), ps);
  const float sigw = sig_np(p.wn[l]);                 // w=0 -> exactly 0.5
  float* vop = p.vo + ((size_t)l * BB + b) * DD + d;
  const float voo = *vop;
  const float von0 = __fadd_rn(voo, __fmul_rn(sigw, __fsub_rn(h, voo)));
  const float th = (l == 0) ? 0.3f : 0.05f;
  const float so = (von0 >= th) ? 1.f : 0.f;
  const float von = __fsub_rn(von0, __fmul_rn(so, th));
  *vop = von;
  s_out[b * DD + d] = so;
  if (lastL) p.dec[b * DD + d] = __fadd_rn(p.dec[b * DD + d], __fmul_rn(so, wk));
}

// ---- decoder (smooth): hd = dec @ decW.T + decb.  grid 16x256 ----
__global__ void k_dec(Prm p)
{
  const int id = blockIdx.x * 256 + threadIdx.x;
  const int b = id >> 9, d = id & 511;
  const float* xr = p.dec + b * DD;
  const float* wr = p.decW + (size_t)d * DD;
  float acc = 0.f;
  for (int j = 0; j < DD; ++j) acc = fmaf(xr[j], wr[j], acc);
  p.hd[b * DD + d] = __fadd_rn(acc, p.decb[d]);
}

// ---- RMS norm (smooth).  grid B x D ----
__global__ void k_rms(Prm p)
{
  __shared__ float rs;
  const int b = blockIdx.x, t = threadIdx.x;
  if (t == 0) {
    float ss = 0.f;
    const float* hr = p.hd + b * DD;
    for (int j = 0; j < DD; ++j) ss = fmaf(hr[j], hr[j], ss);
    rs = 1.f / sqrtf(ss / (float)DD + 1e-6f);
  }
  __syncthreads();
  p.y[b * DD + t] = p.hd[b * DD + t] * rs * p.norm_w[t];
}

// ---- logits (smooth): out[b,ti,:] = y[b] @ embed.T.  grid 192x256 ----
__global__ void k_log(Prm p, int ti)
{
  const int id = blockIdx.x * 256 + threadIdx.x;
  const int b = id / VV, v = id - b * VV;
  const float* yr = p.y + b * DD;
  const float* er = p.embed + (size_t)v * DD;
  float acc = 0.f;
  for (int j = 0; j < DD; ++j) acc = fmaf(yr[j], er[j], acc);
  p.out[((size_t)b * SEQ + ti) * VV + v] = acc;
}

__global__ void k_fill(float* out, float val, int n)
{
  const int i = blockIdx.x * 256 + threadIdx.x;
  if (i < n) out[i] = val;
}

extern "C" void kernel_launch(void* const* d_in, const int* in_sizes, int n_in,
                              void* d_out, int out_size, void* d_ws, size_t ws_size,
                              hipStream_t stream)
{
  (void)in_sizes; (void)n_in; (void)out_size;

  const size_t need = 4096
    + (size_t)2 * LL * BB * HH * 4
    + (size_t)LL * BB * DD * 4
    + (size_t)BB * HH * 4
    + (size_t)2 * BB * DD * 4
    + (size_t)KK * BB * DD * 4
    + (size_t)3 * BB * DD * 4;
  if (ws_size < need) {
    const int n = BB * SEQ * VV;
    k_fill<<<dim3((n + 255) / 256), dim3(256), 0, stream>>>((float*)d_out, 777.f, n);
    return;
  }

  Prm p;
  p.tok    = (const int*)  d_in[0];
  p.embed  = (const float*)d_in[1];
  p.norm_w = (const float*)d_in[2];
  p.encW   = (const float*)d_in[3];
  p.encb   = (const float*)d_in[4];
  p.decW   = (const float*)d_in[5];
  p.decb   = (const float*)d_in[6];
  p.Win    = (const float*)d_in[7];
  p.Wbx    = (const float*)d_in[8];
  p.Wax    = (const float*)d_in[9];
  p.Wtx    = (const float*)d_in[10];
  p.WbV    = (const float*)d_in[11];
  p.WaV    = (const float*)d_in[12];
  p.WtV    = (const float*)d_in[13];
  p.bb     = (const float*)d_in[14];
  p.ba     = (const float*)d_in[15];
  p.bt     = (const float*)d_in[16];
  p.Wg     = (const float*)d_in[17];
  p.Ws     = (const float*)d_in[18];
  p.Wo     = (const float*)d_in[19];
  p.wn     = (const float*)d_in[20];
  p.out    = (float*)d_out;

  char* w = (char*)d_ws;
  size_t off = 4096;
  p.V    = (float*)(w + off); off += (size_t)2 * LL * BB * HH * 4;
  p.vo   = (float*)(w + off); off += (size_t)LL * BB * DD * 4;
  const size_t zero_bytes = off;           // V + vo zero-init each call
  p.sp   = (float*)(w + off); off += (size_t)BB * HH * 4;
  p.sbuf = (float*)(w + off); off += (size_t)2 * BB * DD * 4;
  p.bits = (float*)(w + off); off += (size_t)KK * BB * DD * 4;
  p.dec  = (float*)(w + off); off += (size_t)BB * DD * 4;
  p.hd   = (float*)(w + off); off += (size_t)BB * DD * 4;
  p.y    = (float*)(w + off); off += (size_t)BB * DD * 4;

  (void)hipMemsetAsync(d_ws, 0, zero_bytes, stream);

  for (int ti = 0; ti < SEQ; ++ti) {
    k_enc<<<dim3(BB), dim3(DD), 0, stream>>>(p, ti);
    for (int k = 0; k < KK; ++k) {
      const int rb = k & 1;
      const float wk = exp2f(-(float)(k + 1));
      for (int l = 0; l < LL; ++l) {
        const float* s_in = (l == 0) ? (p.bits + (size_t)k * BB * DD)
                                     : (p.sbuf + (size_t)((l - 1) & 1) * BB * DD);
        float* s_out = p.sbuf + (size_t)(l & 1) * BB * DD;
        k_p1<<<dim3(32), dim3(256), 0, stream>>>(p, l, rb, s_in);
        k_p2<<<dim3(16), dim3(256), 0, stream>>>(p, l, wk, (l == LL - 1) ? 1 : 0,
                                                 s_in, s_out);
      }
    }
    k_dec<<<dim3(16), dim3(256), 0, stream>>>(p);
    k_rms<<<dim3(BB), dim3(DD), 0, stream>>>(p);
    k_log<<<dim3(192), dim3(256), 0, stream>>>(p, ti);
  }
}

// Round 16
// 173112.183 us; speedup vs baseline: 2.9160x; 2.9160x over previous
//
#include <hip/hip_runtime.h>
#include <math.h>

// SNN language model forward — persistent cooperative kernel, BITWISE-faithful
// fp32 numpy emulation (r15 math verbatim), restructured for speed:
//  * each serial-K dot chain -> its own thread (order within chain unchanged)
//  * P1: 7 chains/unit, 448 chain-threads + in-block combine per 8-i slab
//  * P2: 3 chains/unit, in-block combine
//  * grid barriers (r2/r5-proven protocol) instead of kernel launches
// B=8, D=512, H=1024, L=4, K=8, S=64, VOCAB=6144.

#define NWG 128
#define NT  512
#define BB  8
#define DD  512
#define HH  1024
#define LL  4
#define KK  8
#define SEQ 64
#define VV  6144

struct Prm {
  const int*   tok;
  const float *embed, *norm_w, *encW, *encb, *decW, *decb;
  const float *Win, *Wbx, *Wax, *Wtx, *WbV, *WaV, *WtV;
  const float *bb, *ba, *bt, *Wg, *Ws, *Wo, *wn;
  float* out;
  unsigned* cnt;
  unsigned* go;
  float* V;        // [2][L][B][H] double-buffered by bit parity
  float* vo;       // [L][B][D]
  float *sp, *sbuf, *bits, *dec, *hd, *y;
};

// ---- r15 math, verbatim ----
__device__ __forceinline__ float expf_cr(float x)  { return (float)exp((double)x); }
__device__ __forceinline__ float log1pf_cr(float x){ return (float)log1p((double)x); }
__device__ __forceinline__ float sig_np(float x) {
  const float t = expf_cr(-x);
  const float u = __fadd_rn(1.f, t);
  return 1.f / u;
}
__device__ __forceinline__ float sp_np(float x) {
  const float ax = fabsf(x);
  const float t = expf_cr(-ax);
  const float u = log1pf_cr(t);
  return __fadd_rn(fmaxf(x, 0.f), u);
}
__device__ __forceinline__ float4 ld4(const float* p) { return *(const float4*)p; }

// serial ascending-j fp32 FMA dot (float4 loads, scalar-serial processing)
__device__ __forceinline__ float serdot(const float* __restrict__ x,
                                        const float* __restrict__ w, int K)
{
  float acc = 0.f;
  for (int j = 0; j < K; j += 4) {
    const float4 xv = ld4(x + j);
    const float4 wv = ld4(w + j);
    acc = fmaf(xv.x, wv.x, acc);
    acc = fmaf(xv.y, wv.y, acc);
    acc = fmaf(xv.z, wv.z, acc);
    acc = fmaf(xv.w, wv.w, acc);
  }
  return acc;
}

__global__ void __launch_bounds__(NT) k_fill(float* out, float val, int n)
{
  const int i = blockIdx.x * NT + threadIdx.x;
  if (i < n) out[i] = val;
}

__global__ void __launch_bounds__(NT)
snn_kernel(Prm p)
{
  const int wg = blockIdx.x;
  const int t  = threadIdx.x;
  const int vt = wg * NT + t;

  __shared__ float part[7 * 64];
  unsigned nbar = 0;

  auto GBAR = [&]() {
    ++nbar;
    __syncthreads();
    if (t == 0) {
      __hip_atomic_fetch_add(&p.cnt[(wg & 7) * 32], 1u, __ATOMIC_RELEASE, __HIP_MEMORY_SCOPE_AGENT);
      if (wg == 0) {
        const unsigned need = nbar * (NWG / 8);
        for (int c = 0; c < 8; ++c) {
          while (__hip_atomic_load(&p.cnt[c * 32], __ATOMIC_RELAXED, __HIP_MEMORY_SCOPE_AGENT) < need)
            __builtin_amdgcn_s_sleep(1);
        }
        __hip_atomic_store(p.go, nbar, __ATOMIC_RELEASE, __HIP_MEMORY_SCOPE_AGENT);
      } else {
        while (__hip_atomic_load(p.go, __ATOMIC_RELAXED, __HIP_MEMORY_SCOPE_AGENT) < nbar)
          __builtin_amdgcn_s_sleep(1);
      }
      __builtin_amdgcn_fence(__ATOMIC_ACQUIRE, "agent");
    }
    __syncthreads();
  };

  // ---- encoder for token ti, thread ids offset by vbase (r15 math) ----
  auto ENC = [&](int ti, int vbase) {
    const int e = vt - vbase;
    if (e >= 0 && e < BB * DD) {
      const int b = e >> 9, d = e & 511;
      const int tok = p.tok[b * SEQ + ti];
      const float* er = p.embed + (size_t)tok * DD;
      const float* wr = p.encW + (size_t)d * DD;
      const float acc = serdot(er, wr, DD);
      const float z = __fadd_rn(acc, p.encb[d]);
      float r = sig_np(z);
      for (int kk = 0; kk < KK; ++kk) {
        const float bit = (r >= 0.5f) ? 1.f : 0.f;
        p.bits[((size_t)kk * BB + b) * DD + d] = bit;
        r = __fmul_rn(__fsub_rn(r, __fmul_rn(0.5f, bit)), 2.f);
      }
      p.dec[b * DD + d] = 0.f;
    }
  };

  // ---- P1: block wg owns i in [wg*8, wg*8+8), all 8 b.  7 chains/unit ----
  auto P1 = [&](int l, int rb, const float* __restrict__ s_in) {
    const float* Vrd = p.V + ((size_t)rb * LL + l) * BB * HH;
    if (t < 448) {
      const int c = t >> 6, u = t & 63;
      const int b = u & 7, i = wg * 8 + (u >> 3);
      float acc;
      if (c < 4) {
        const size_t row = ((size_t)l * HH + i) * DD;
        const float* wr = (c == 0 ? p.Win : c == 1 ? p.Wbx : c == 2 ? p.Wax : p.Wtx) + row;
        acc = serdot(s_in + b * DD, wr, DD);
      } else {
        const size_t row = ((size_t)l * HH + i) * HH;
        const float* wr = (c == 4 ? p.WbV : c == 5 ? p.WaV : p.WtV) + row;
        acc = serdot(Vrd + b * HH, wr, HH);
      }
      part[c * 64 + u] = acc;
    }
    __syncthreads();
    if (t < 64) {
      const int u = t, b = u & 7, i = wg * 8 + (u >> 3);
      const float uacc = part[0 * 64 + u];
      const float zb = __fadd_rn(__fadd_rn(part[1 * 64 + u], part[4 * 64 + u]), p.bb[l * HH + i]);
      const float za = __fadd_rn(__fadd_rn(part[2 * 64 + u], part[5 * 64 + u]), p.ba[l * HH + i]);
      const float zt = __fadd_rn(__fadd_rn(part[3 * 64 + u], part[6 * 64 + u]), p.bt[l * HH + i]);
      const float beta  = sig_np(zb);
      const float alpha = sig_np(za);
      const float vth   = __fadd_rn(0.1f, sp_np(zt));
      const float Vn0   = __fadd_rn(__fmul_rn(beta, Vrd[b * HH + i]), __fmul_rn(alpha, uacc));
      const float spv   = (Vn0 >= vth) ? 1.f : 0.f;
      const float Vn    = __fsub_rn(Vn0, __fmul_rn(spv, vth));
      p.V[(((size_t)(1 - rb) * LL + l) * BB + b) * HH + i] = Vn;
      p.sp[b * HH + i] = spv;
    }
    __syncthreads();
  };

  // ---- P2: block wg owns d in [wg*4, wg*4+4), all 8 b.  3 chains/unit ----
  auto P2 = [&](int l, int k, const float* __restrict__ s_in, float* __restrict__ s_out) {
    if (t < 192 && (t & 63) < 32) {
      const int c = t >> 6, u = t & 31;
      const int b = u & 7, d = wg * 4 + (u >> 3);
      float acc;
      if (c == 0) {
        acc = serdot(p.sp + b * HH, p.Wo + ((size_t)l * DD + d) * HH, HH);
      } else if (c == 1) {
        acc = serdot(s_in + b * DD, p.Wg + ((size_t)l * DD + d) * DD, DD);
      } else {
        acc = serdot(s_in + b * DD, p.Ws + ((size_t)l * DD + d) * DD, DD);
      }
      part[c * 32 + u] = acc;
    }
    __syncthreads();
    if (t < 32) {
      const int u = t, b = u & 7, d = wg * 4 + (u >> 3);
      const float po = part[0 * 32 + u];
      const float pg = part[1 * 32 + u];
      const float ps = part[2 * 32 + u];
      const float g  = sig_np(pg);
      const float h  = __fadd_rn(__fmul_rn(g, po), ps);
      const float sigw = sig_np(p.wn[l]);
      float* vop = p.vo + ((size_t)l * BB + b) * DD + d;
      const float voo = *vop;
      const float von0 = __fadd_rn(voo, __fmul_rn(sigw, __fsub_rn(h, voo)));
      const float th = (l == 0) ? 0.3f : 0.05f;
      const float so = (von0 >= th) ? 1.f : 0.f;
      const float von = __fsub_rn(von0, __fmul_rn(so, th));
      *vop = von;
      s_out[b * DD + d] = so;
      if (l == LL - 1) {
        const float wk = exp2f(-(float)(k + 1));
        p.dec[b * DD + d] = __fadd_rn(p.dec[b * DD + d], __fmul_rn(so, wk));
      }
    }
    __syncthreads();
  };

  // ---- decoder matmul (smooth path, r15 math) ----
  auto DEC = [&]() {
    if (vt < BB * DD) {
      const int b = vt >> 9, d = vt & 511;
      const float acc = serdot(p.dec + b * DD, p.decW + (size_t)d * DD, DD);
      p.hd[b * DD + d] = __fadd_rn(acc, p.decb[d]);
    }
  };

  // ---- RMS norm (each thread redundantly computes its b's sum; same order) ----
  auto RMS = [&]() {
    if (vt < BB * DD) {
      const int b = vt >> 9, d = vt & 511;
      const float* hr = p.hd + b * DD;
      float ss = 0.f;
      for (int j = 0; j < DD; ++j) ss = fmaf(hr[j], hr[j], ss);
      const float rs = 1.f / sqrtf(ss / (float)DD + 1e-6f);
      p.y[b * DD + d] = p.hd[b * DD + d] * rs * p.norm_w[d];
    }
  };

  // ---- logits (ti) in [0, B*V); encoder(ti+1) in [B*V, B*V + B*D) ----
  auto LOGENC = [&](int ti) {
    if (vt < BB * VV) {
      const int b = vt / VV, v = vt - b * VV;
      const float acc = serdot(p.y + b * DD, p.embed + (size_t)v * DD, DD);
      p.out[((size_t)b * SEQ + ti) * VV + v] = acc;
    }
    if (ti + 1 < SEQ) ENC(ti + 1, BB * VV);
  };

  // ================= main sequence =================
  ENC(0, 0);
  GBAR();
  for (int ti = 0; ti < SEQ; ++ti) {
    for (int k = 0; k < KK; ++k) {
      const int rb = k & 1;
      for (int l = 0; l < LL; ++l) {
        const float* s_in = (l == 0) ? (p.bits + (size_t)k * BB * DD)
                                     : (p.sbuf + (size_t)((l - 1) & 1) * BB * DD);
        float* s_out = p.sbuf + (size_t)(l & 1) * BB * DD;
        P1(l, rb, s_in);
        GBAR();
        P2(l, k, s_in, s_out);
        GBAR();
      }
    }
    DEC(); GBAR();
    RMS(); GBAR();
    LOGENC(ti); GBAR();
  }
}

extern "C" void kernel_launch(void* const* d_in, const int* in_sizes, int n_in,
                              void* d_out, int out_size, void* d_ws, size_t ws_size,
                              hipStream_t stream)
{
  (void)in_sizes; (void)n_in; (void)out_size;

  const size_t need = 2048
    + (size_t)2 * LL * BB * HH * 4   // V
    + (size_t)LL * BB * DD * 4       // vo
    + (size_t)BB * HH * 4            // sp
    + (size_t)2 * BB * DD * 4        // sbuf
    + (size_t)KK * BB * DD * 4       // bits
    + (size_t)3 * BB * DD * 4;       // dec, hd, y
  if (ws_size < need) {
    const int n = BB * SEQ * VV;
    k_fill<<<dim3((n + NT - 1) / NT), dim3(NT), 0, stream>>>((float*)d_out, 777.f, n);
    return;
  }

  Prm p;
  p.tok    = (const int*)  d_in[0];
  p.embed  = (const float*)d_in[1];
  p.norm_w = (const float*)d_in[2];
  p.encW   = (const float*)d_in[3];
  p.encb   = (const float*)d_in[4];
  p.decW   = (const float*)d_in[5];
  p.decb   = (const float*)d_in[6];
  p.Win    = (const float*)d_in[7];
  p.Wbx    = (const float*)d_in[8];
  p.Wax    = (const float*)d_in[9];
  p.Wtx    = (const float*)d_in[10];
  p.WbV    = (const float*)d_in[11];
  p.WaV    = (const float*)d_in[12];
  p.WtV    = (const float*)d_in[13];
  p.bb     = (const float*)d_in[14];
  p.ba     = (const float*)d_in[15];
  p.bt     = (const float*)d_in[16];
  p.Wg     = (const float*)d_in[17];
  p.Ws     = (const float*)d_in[18];
  p.Wo     = (const float*)d_in[19];
  p.wn     = (const float*)d_in[20];
  p.out    = (float*)d_out;

  char* w = (char*)d_ws;
  size_t off = 0;
  p.cnt  = (unsigned*)(w + off); off += 1024;                          // 8 buckets x 128B
  p.go   = (unsigned*)(w + off); off += 1024;
  p.V    = (float*)(w + off);    off += (size_t)2 * LL * BB * HH * 4;  // 256 KB
  p.vo   = (float*)(w + off);    off += (size_t)LL * BB * DD * 4;      // 64 KB
  const size_t zero_bytes = off;  // barrier state + V + vo zeroed each call
  p.sp   = (float*)(w + off);    off += (size_t)BB * HH * 4;
  p.sbuf = (float*)(w + off);    off += (size_t)2 * BB * DD * 4;
  p.bits = (float*)(w + off);    off += (size_t)KK * BB * DD * 4;
  p.dec  = (float*)(w + off);    off += (size_t)BB * DD * 4;
  p.hd   = (float*)(w + off);    off += (size_t)BB * DD * 4;
  p.y    = (float*)(w + off);    off += (size_t)BB * DD * 4;

  (void)hipMemsetAsync(d_ws, 0, zero_bytes, stream);

  void* args[] = { (void*)&p };
  hipError_t e = hipLaunchCooperativeKernel((const void*)snn_kernel,
                                            dim3(NWG), dim3(NT), args, 0, stream);
  if (e != hipSuccess) {
    // 128 WGs x 512 thr, ~2 KB LDS -> trivially co-resident on 256 CUs.
    snn_kernel<<<dim3(NWG), dim3(NT), 0, stream>>>(p);
  }
}